// Round 7
// baseline (585.006 us; speedup 1.0000x reference)
//
#include <hip/hip_runtime.h>

typedef unsigned short u16;
typedef unsigned int u32;
typedef __bf16 bf16x8 __attribute__((ext_vector_type(8)));
typedef float f32x4 __attribute__((ext_vector_type(4)));

#define TT 6
#define NTOK (6*40*72)      // 17280 tokens
#define KTOT 373            // keys per frame: 45 win + 148 rolled + 180 pooled
#define NKEYS (TT*KTOT)     // 2238 dense keys
#define KC 64               // keys per chunk
#define NCH 35              // ceil(2238/64)
#define QSC 0.12751745f     // 1/sqrt(128) * log2(e), folded into Wq/bq

__device__ __forceinline__ float bf2f(u16 u){ u32 x = ((u32)u) << 16; return __builtin_bit_cast(float, x); }
__device__ __forceinline__ u16 f2bf(float f){ u32 x = __builtin_bit_cast(u32, f); x += 0x7fff + ((x >> 16) & 1); return (u16)(x >> 16); }

// ---------------- float32 -> bf16 conversion (x) ----------------
__global__ __launch_bounds__(256) void convert_x(const float* __restrict__ src, u16* __restrict__ dst, int n4)
{
  int i = blockIdx.x * 256 + threadIdx.x;
  if (i >= n4) return;
  float4 v = *(const float4*)(src + (size_t)i * 4);
  u16 o[4] = {f2bf(v.x), f2bf(v.y), f2bf(v.z), f2bf(v.w)};
  *(uint2*)(dst + (size_t)i * 4) = *(const uint2*)o;
}

// ---------------- weight transpose: out[m][n][k] = bf16(W_m[k][n]); Wq scaled by QSC ----------------
__global__ __launch_bounds__(256) void transpose_w(
    const float* __restrict__ w0, const float* __restrict__ w1,
    const float* __restrict__ w2, const float* __restrict__ w3, u16* __restrict__ out)
{
  int m = blockIdx.y;
  const float* src = m == 0 ? w0 : (m == 1 ? w1 : (m == 2 ? w2 : w3));
  float sc = (m == 0) ? QSC : 1.f;
  int idx = blockIdx.x * 256 + threadIdx.x;   // = n*512 + k
  int n = idx >> 9, k = idx & 511;
  out[m * 262144 + idx] = f2bf(src[k * 512 + n] * sc);
}

// ---------------- GEMM: C[M][512] = A[M][512] @ W + bias ----------------
__global__ __launch_bounds__(256) void gemm_bias(
    const u16* __restrict__ A, const u16* __restrict__ wt,
    const float* __restrict__ b0, const float* __restrict__ b1, const float* __restrict__ b2,
    u16* __restrict__ c0, u16* __restrict__ c1, u16* __restrict__ c2, float* __restrict__ cf,
    int wo0, int wo1, int wo2, float bsc0, int M)
{
  __shared__ __align__(16) u16 sA[128][40];
  __shared__ __align__(16) u16 sB[128][40];
  int z = blockIdx.z;
  const u16* Bt = wt + (size_t)(z == 0 ? wo0 : (z == 1 ? wo1 : wo2)) * 262144;
  const float* bias = z == 0 ? b0 : (z == 1 ? b1 : b2);
  float bsc = (z == 0) ? bsc0 : 1.f;
  u16* Cout = z == 0 ? c0 : (z == 1 ? c1 : c2);
  int mbase = blockIdx.x * 128, nbase = blockIdx.y * 128;
  int tid = threadIdx.x, lane = tid & 63, wave = tid >> 6;
  int wm = (wave >> 1) * 64, wn = (wave & 1) * 64;
  int quad = lane >> 4, tr = lane & 15;
  f32x4 acc[4][4];
#pragma unroll
  for (int i = 0; i < 4; i++)
#pragma unroll
    for (int j = 0; j < 4; j++){ acc[i][j][0]=0.f; acc[i][j][1]=0.f; acc[i][j][2]=0.f; acc[i][j][3]=0.f; }

  for (int k0 = 0; k0 < 512; k0 += 32){
    if (k0) __syncthreads();
#pragma unroll
    for (int r = 0; r < 2; r++){
      int u = tid + 256 * r;
      int row = u >> 2, kg = (u & 3) * 8;
      int grow = mbase + row;
      uint4 va = make_uint4(0,0,0,0);
      if (grow < M) va = *(const uint4*)(A + (size_t)grow * 512 + k0 + kg);
      *(uint4*)(&sA[row][kg]) = va;
      uint4 vb = *(const uint4*)(Bt + (size_t)(nbase + row) * 512 + k0 + kg);
      *(uint4*)(&sB[row][kg]) = vb;
    }
    __syncthreads();
    bf16x8 a[4], b[4];
#pragma unroll
    for (int i = 0; i < 4; i++) a[i] = *(const bf16x8*)(&sA[wm + i*16 + tr][quad * 8]);
#pragma unroll
    for (int j = 0; j < 4; j++) b[j] = *(const bf16x8*)(&sB[wn + j*16 + tr][quad * 8]);
#pragma unroll
    for (int i = 0; i < 4; i++)
#pragma unroll
      for (int j = 0; j < 4; j++)
        acc[i][j] = __builtin_amdgcn_mfma_f32_16x16x32_bf16(a[i], b[j], acc[i][j], 0, 0, 0);
  }

#pragma unroll
  for (int j = 0; j < 4; j++){
    int col = nbase + wn + j*16 + tr;
    float bv = bias[col] * bsc;
#pragma unroll
    for (int i = 0; i < 4; i++)
#pragma unroll
      for (int r2 = 0; r2 < 4; r2++){
        int row = mbase + wm + i*16 + quad*4 + r2;
        if (row < M){
          float val = acc[i][j][r2] + bv;
          if (cf) cf[(size_t)row * 512 + col] = val;
          else    Cout[(size_t)row * 512 + col] = f2bf(val);
        }
      }
  }
}

// ---------------- depthwise 4x4/4 pool conv: px[1080][512] bf16 ----------------
__global__ __launch_bounds__(256) void pool_conv(
    const float* __restrict__ x, const float* __restrict__ pw,
    const float* __restrict__ pb, u16* __restrict__ px)
{
  int idx = blockIdx.x * 256 + threadIdx.x;
  int c = idx & 511, n = idx >> 9;
  int f = n / 180, rp = n % 180, ph = rp / 18, pwc = rp % 18;
  float acc = pb[c];
#pragma unroll
  for (int i = 0; i < 4; i++)
#pragma unroll
    for (int j = 0; j < 4; j++){
      int hh = ph*4 + i, ww = pwc*4 + j;
      acc += x[((size_t)((f*40 + hh)*72 + ww)) * 512 + c] * pw[(i*4 + j)*512 + c];
    }
  px[idx] = f2bf(acc);
}

// ---------------- window mask + VALID_IND compaction (parallel) ----------------
// grid 64 blocks (one per window) x 64 threads; ballot-reduce the 270 mask reads.
__global__ __launch_bounds__(64) void prep(const float* __restrict__ masks, int* __restrict__ wmask, int* __restrict__ vi)
{
  int win = blockIdx.x, tid = threadIdx.x;
  int wi = win >> 3, wj = win & 7;
  int flag = 0;
  for (int p = tid; p < 270; p += 64){   // p = f*45 + pos
    int f = p / 45, pos = p - f*45;
    int hh = wi*5 + pos/9, ww = wj*9 + pos%9;
    if (masks[(f*40 + hh)*72 + ww] > 0.f) flag = 1;
  }
  unsigned long long b = __ballot(flag);
  if (tid == 0) wmask[win] = (b != 0ULL) ? 1 : 0;
  if (win == 0 && tid == 0){
    int cnt = 0;
    for (int e = 0; e < 180; e++){
      int s = e / 45, pos = e % 45, pr = pos / 9, pc = pos % 9;
      bool inval = (s == 0 && pr < 2 && pc < 4) || (s == 1 && pr < 2 && pc >= 5) ||
                   (s == 2 && pr >= 3 && pc < 4) || (s == 3 && pr >= 3 && pc >= 5);
      if (!inval) vi[cnt++] = e;
    }
  }
}

// ================= DENSE attention =================
// Block = (window, head, half). half = frames [3*half, 3*half+3). M = 144 rows
// (3 frames x 48-pad) = 9 m-tiles. Waves 0-7 own tiles 0-7 (rows 0..127).
// Tile 8 (rows 128..143 = frame 2 local 32..47): QK+den by wave 0 ALONE;
// PV by waves 4-7 (2 hd-tiles each). KC=64 keys/chunk, 35 chunks.
// Grid 1024 -> ~2 blocks/CU. __launch_bounds__(512,4) caps unified VGPR+AGPR
// at 128/wave; qf8 therefore lives in NO register across the loop — wave 0
// reloads it from global each chunk (L1-resident, exec-masked) [round-6 spill fix].
__global__ __launch_bounds__(512, 4) void attn_dense(
    const u16* __restrict__ qb, const u16* __restrict__ kb, const u16* __restrict__ vb,
    const int* __restrict__ wmaskp, const int* __restrict__ vip,
    u16* __restrict__ yb)
{
  __shared__ __align__(16) u16 sK[64][136];   // key chunk [key][hd]
  __shared__ __align__(16) u16 sVt[128][72];  // V^T [hd][key]
  __shared__ __align__(16) u16 sP[144][72];   // exp(S) bf16 [row][key]
  __shared__ u16 sIdx16[2240];                // key -> unified row (pool rows at NTOK+)
  __shared__ int sVI[148];
  __shared__ float sDenX[16];                 // tile-8 den (written by wave 0 only)

  int win = blockIdx.x, head = blockIdx.y, half = blockIdx.z;
  if (!wmaskp[win]) return;
  int wi = win >> 3, wj = win & 7;
  int tid = threadIdx.x, lane = tid & 63, wave = tid >> 6;
  int quad = lane >> 4, tr = lane & 15;
  int hoff = head * 128;

  if (tid < 148) sVI[tid] = vip[tid];
  __syncthreads();

  // ---- per-window gather table (u16 unified row indices) ----
  for (int i = tid; i < 2240; i += 512){
    int v = 0;
    if (i < NKEYS){
      int f = i / KTOT, slot = i - f * KTOT;
      if (slot < 45){
        v = (f*40 + wi*5 + slot/9)*72 + wj*9 + slot%9;
      } else if (slot < 193){
        int e = sVI[slot - 45];
        int s2 = e/45, pos = e - s2*45, pr = pos/9, pc = pos - pr*9;
        int hh = wi*5 + pr + ((s2 < 2) ? 3 : -3);
        int ww = wj*9 + pc + ((s2 & 1) ? -5 : 5);
        if (hh < 0) hh += 40; else if (hh >= 40) hh -= 40;
        if (ww < 0) ww += 72; else if (ww >= 72) ww -= 72;
        v = (f*40 + hh)*72 + ww;
      } else {
        v = NTOK + f*180 + (slot - 193);
      }
    }
    sIdx16[i] = (u16)v;
  }

  // ---- Q fragments in registers: own tile only (tile 8 reloaded per chunk) ----
  bf16x8 qf[4];
  const u16* qp8;
  bool v8;
  {
    int row = wave*16 + tr;              // 0..143
    int fl = row / 48, r = row - fl*48;
    bool vq = r < 45;
    const u16* qp = qb + ((size_t)(((3*half + fl)*40 + wi*5 + r/9)*72 + wj*9 + r%9))*512 + hoff;
#pragma unroll
    for (int kt = 0; kt < 4; kt++){
      uint4 v = make_uint4(0,0,0,0);
      if (vq) v = *(const uint4*)(qp + kt*32 + quad*8);
      qf[kt] = __builtin_bit_cast(bf16x8, v);
    }
    int r8 = 32 + tr;                    // tile 8 = frame 2, local rows 32..47
    v8 = (wave == 0) && (r8 < 45);
    int r8c = (r8 < 45) ? r8 : 44;       // clamp for safe address
    qp8 = qb + ((size_t)(((3*half + 2)*40 + wi*5 + r8c/9)*72 + wj*9 + r8c%9))*512 + hoff;
  }

  f32x4 accv[8], accx[2];
#pragma unroll
  for (int nt = 0; nt < 8; nt++){ accv[nt][0]=0.f; accv[nt][1]=0.f; accv[nt][2]=0.f; accv[nt][3]=0.f; }
  accx[0][0]=0.f; accx[0][1]=0.f; accx[0][2]=0.f; accx[0][3]=0.f;
  accx[1][0]=0.f; accx[1][1]=0.f; accx[1][2]=0.f; accx[1][3]=0.f;
  float dacc[4] = {0.f,0.f,0.f,0.f}, dacc8[4] = {0.f,0.f,0.f,0.f};

  __syncthreads();   // sIdx16 ready

  // register prefetch (2 uint4 for K, 2 for V per thread per chunk)
  uint4 pfk[2], pfv[2];
  auto pref = [&](int ch){
#pragma unroll
    for (int r = 0; r < 2; r++){ pfk[r] = make_uint4(0,0,0,0); pfv[r] = make_uint4(0,0,0,0); }
    if (ch < NCH){
#pragma unroll
      for (int r = 0; r < 2; r++){
        int u = tid + 512*r;
        int jgk = ch*64 + (u >> 4);
        if (jgk < NKEYS)
          pfk[r] = *(const uint4*)(kb + ((size_t)sIdx16[jgk] << 9) + hoff + (u & 15)*8);
        int jgv = ch*64 + (u & 63);
        if (jgv < NKEYS)
          pfv[r] = *(const uint4*)(vb + ((size_t)sIdx16[jgv] << 9) + hoff + (u >> 6)*8);
      }
    }
  };
  pref(0);

  for (int ch = 0; ch < NCH; ch++){
    __syncthreads();               // prev PV done; sK/sVt free
#pragma unroll
    for (int r = 0; r < 2; r++){
      int u = tid + 512*r;
      *(uint4*)(&sK[u >> 4][(u & 15)*8]) = pfk[r];
      int keyv = u & 63, dgv = u >> 6;
      u32 vv[4] = {pfv[r].x, pfv[r].y, pfv[r].z, pfv[r].w};
#pragma unroll
      for (int q2 = 0; q2 < 4; q2++){
        sVt[dgv*8 + q2*2][keyv]     = (u16)(vv[q2] & 0xffff);
        sVt[dgv*8 + q2*2 + 1][keyv] = (u16)(vv[q2] >> 16);
      }
    }
    __syncthreads();               // staged
    pref(ch + 1);                  // overlap next gather with compute

    // tile-8 Q fragments: wave 0 reloads from global (L1-hit after chunk 0)
    bf16x8 qf8[4];
#pragma unroll
    for (int kt = 0; kt < 4; kt++){
      uint4 v = make_uint4(0,0,0,0);
      if (v8) v = *(const uint4*)(qp8 + kt*32 + quad*8);
      qf8[kt] = __builtin_bit_cast(bf16x8, v);
    }

    // ---- QK^T + exp2 (Q pre-scaled by 1/sqrt(hd)*log2e) ----
#pragma unroll
    for (int nt = 0; nt < 4; nt++){
      bf16x8 bk4[4];
#pragma unroll
      for (int kt = 0; kt < 4; kt++) bk4[kt] = *(const bf16x8*)(&sK[nt*16 + tr][kt*32 + quad*8]);
      int colg = ch*64 + nt*16 + tr;
      bool vld = colg < NKEYS;
      f32x4 s = {0.f, 0.f, 0.f, 0.f};
#pragma unroll
      for (int kt = 0; kt < 4; kt++) s = __builtin_amdgcn_mfma_f32_16x16x32_bf16(qf[kt], bk4[kt], s, 0, 0, 0);
#pragma unroll
      for (int r2 = 0; r2 < 4; r2++){
        float p = vld ? __builtin_amdgcn_exp2f(s[r2]) : 0.f;   // no max-sub: logits small
        u16 pb2 = f2bf(p);
        sP[wave*16 + quad*4 + r2][nt*16 + tr] = pb2;
        dacc[r2] += bf2f(pb2);
      }
      if (wave == 0){              // tile-8 QK: wave 0 does ALL n-tiles
        f32x4 s8 = {0.f, 0.f, 0.f, 0.f};
#pragma unroll
        for (int kt = 0; kt < 4; kt++) s8 = __builtin_amdgcn_mfma_f32_16x16x32_bf16(qf8[kt], bk4[kt], s8, 0, 0, 0);
#pragma unroll
        for (int r2 = 0; r2 < 4; r2++){
          float p = vld ? __builtin_amdgcn_exp2f(s8[r2]) : 0.f;
          u16 pb2 = f2bf(p);
          sP[128 + quad*4 + r2][nt*16 + tr] = pb2;
          dacc8[r2] += bf2f(pb2);
        }
      }
    }
    __syncthreads();               // sP complete

    // ---- PV: own tile, all 8 hd-tiles ----
#pragma unroll
    for (int kt = 0; kt < 2; kt++){
      bf16x8 a = *(const bf16x8*)(&sP[wave*16 + tr][kt*32 + quad*8]);
#pragma unroll
      for (int nt = 0; nt < 8; nt++){
        bf16x8 bv = *(const bf16x8*)(&sVt[nt*16 + tr][kt*32 + quad*8]);
        accv[nt] = __builtin_amdgcn_mfma_f32_16x16x32_bf16(a, bv, accv[nt], 0, 0, 0);
      }
    }
    // ---- PV: tile 8, waves 4-7 take 2 hd-tiles each ----
    if (wave >= 4){
      int h0 = 2*(wave - 4);
#pragma unroll
      for (int kt = 0; kt < 2; kt++){
        bf16x8 a8 = *(const bf16x8*)(&sP[128 + tr][kt*32 + quad*8]);
#pragma unroll
        for (int j = 0; j < 2; j++){
          bf16x8 bv = *(const bf16x8*)(&sVt[(h0 + j)*16 + tr][kt*32 + quad*8]);
          accx[j] = __builtin_amdgcn_mfma_f32_16x16x32_bf16(a8, bv, accx[j], 0, 0, 0);
        }
      }
    }
  }

  // ---- tile-8 den: wave 0 holds the complete sum; plain store ----
  if (wave == 0){
#pragma unroll
    for (int r2 = 0; r2 < 4; r2++){
      float d = dacc8[r2];
      d += __shfl_xor(d, 1, 64); d += __shfl_xor(d, 2, 64);
      d += __shfl_xor(d, 4, 64); d += __shfl_xor(d, 8, 64);
      if (tr == 0) sDenX[quad*4 + r2] = d;
    }
  }
  __syncthreads();

  // ---- own-tile epilogue ----
#pragma unroll
  for (int r2 = 0; r2 < 4; r2++){
    float d = dacc[r2];
    d += __shfl_xor(d, 1, 64); d += __shfl_xor(d, 2, 64);
    d += __shfl_xor(d, 4, 64); d += __shfl_xor(d, 8, 64);
    float dinv = 1.f / d;
    int row = wave*16 + quad*4 + r2;
    int fl = row / 48, r = row - fl*48;
    if (r < 45){
      size_t base = ((size_t)(((3*half + fl)*40 + wi*5 + r/9)*72 + wj*9 + r%9))*512 + hoff;
#pragma unroll
      for (int nt = 0; nt < 8; nt++)
        yb[base + nt*16 + tr] = f2bf(accv[nt][r2] * dinv);
    }
  }
  // ---- tile-8 epilogue (waves 4-7 hold accx) ----
  if (wave >= 4){
    int h0 = 2*(wave - 4);
#pragma unroll
    for (int r2 = 0; r2 < 4; r2++){
      int r = 32 + quad*4 + r2;
      if (r < 45){
        float dinv = 1.f / sDenX[quad*4 + r2];
        size_t base = ((size_t)(((3*half + 2)*40 + wi*5 + r/9)*72 + wj*9 + r%9))*512 + hoff;
#pragma unroll
        for (int j = 0; j < 2; j++)
          yb[base + (h0 + j)*16 + tr] = f2bf(accx[j][r2] * dinv);
      }
    }
  }
}

// ---------------- LOCAL (unmasked) windows: per-frame 45-key attention ----------------
__device__ __forceinline__ const u16* key_src_local(int slot, int qf, int wi, int wj, int head,
    const u16* __restrict__ tokbuf)
{
  int hh = wi*5 + slot/9, ww = wj*9 + slot%9;
  return tokbuf + ((size_t)((qf*40 + hh)*72 + ww)) * 512 + head * 128;
}

__global__ __launch_bounds__(256) void attn_local(
    const u16* __restrict__ qb, const u16* __restrict__ kb, const u16* __restrict__ vb,
    const int* __restrict__ wmaskp, u16* __restrict__ yb)
{
  __shared__ __align__(16) u16 sQ[48][136];
  __shared__ __align__(16) u16 sK[64][136];
  __shared__ __align__(16) u16 sVt[128][72];
  __shared__ __align__(16) u16 sP[48][72];
  __shared__ float sDen[48];

  int win = blockIdx.x, head = blockIdx.y, qf = blockIdx.z;
  if (wmaskp[win]) return;
  int wi = win >> 3, wj = win & 7;
  int tid = threadIdx.x, lane = tid & 63, wave = tid >> 6;
  int quad = lane >> 4, tr = lane & 15;

  if (tid < 48) sDen[tid] = 0.f;

#pragma unroll
  for (int r = 0; r < 3; r++){
    int u = tid + 256 * r;
    int row = u >> 4, dg = u & 15;
    uint4 val = make_uint4(0,0,0,0);
    if (row < 45){
      int hh = wi*5 + row/9, ww = wj*9 + row%9;
      val = *(const uint4*)(qb + ((size_t)((qf*40 + hh)*72 + ww)) * 512 + head*128 + dg*8);
    }
    *(uint4*)(&sQ[row][dg * 8]) = val;
  }

  const int nkeys = 45;
  f32x4 acc[3][2];
#pragma unroll
  for (int a = 0; a < 3; a++)
#pragma unroll
    for (int b = 0; b < 2; b++){ acc[a][b][0]=0.f; acc[a][b][1]=0.f; acc[a][b][2]=0.f; acc[a][b][3]=0.f; }

#pragma unroll
  for (int r = 0; r < 4; r++){
    int u = tid + 256 * r;
    int key = u >> 4, dg = u & 15;
    uint4 val = make_uint4(0,0,0,0);
    if (key < nkeys) val = *(const uint4*)(key_src_local(key, qf, wi, wj, head, kb) + dg * 8);
    *(uint4*)(&sK[key][dg * 8]) = val;
  }
#pragma unroll
  for (int r = 0; r < 4; r++){
    int u = tid + 256 * r;
    int key = u & 63, dg = u >> 6;
    uint4 val = make_uint4(0,0,0,0);
    if (key < nkeys) val = *(const uint4*)(key_src_local(key, qf, wi, wj, head, vb) + dg * 8);
    u32 vv[4] = {val.x, val.y, val.z, val.w};
#pragma unroll
    for (int q2 = 0; q2 < 4; q2++){
      sVt[dg*8 + q2*2][key]     = (u16)(vv[q2] & 0xffff);
      sVt[dg*8 + q2*2 + 1][key] = (u16)(vv[q2] >> 16);
    }
  }
  __syncthreads();

#pragma unroll
  for (int mt = 0; mt < 3; mt++){
    f32x4 sacc = {0.f, 0.f, 0.f, 0.f};
#pragma unroll
    for (int kt = 0; kt < 4; kt++){
      bf16x8 a = *(const bf16x8*)(&sQ[mt*16 + tr][kt*32 + quad*8]);
      bf16x8 b = *(const bf16x8*)(&sK[wave*16 + tr][kt*32 + quad*8]);
      sacc = __builtin_amdgcn_mfma_f32_16x16x32_bf16(a, b, sacc, 0, 0, 0);
    }
    int colg = wave * 16 + tr;
    float pr4[4];
#pragma unroll
    for (int r2 = 0; r2 < 4; r2++){
      float p = (colg < nkeys) ? __builtin_amdgcn_exp2f(sacc[r2]) : 0.f;  // Q pre-scaled
      u16 pb2 = f2bf(p);
      sP[mt*16 + quad*4 + r2][wave*16 + tr] = pb2;
      pr4[r2] = bf2f(pb2);
    }
#pragma unroll
    for (int r2 = 0; r2 < 4; r2++){
      float ps = pr4[r2];
      ps += __shfl_xor(ps, 1, 64);
      ps += __shfl_xor(ps, 2, 64);
      ps += __shfl_xor(ps, 4, 64);
      ps += __shfl_xor(ps, 8, 64);
      if (tr == 0) atomicAdd(&sDen[mt*16 + quad*4 + r2], ps);
    }
  }
  __syncthreads();

#pragma unroll
  for (int mt = 0; mt < 3; mt++)
#pragma unroll
    for (int nt = 0; nt < 2; nt++)
#pragma unroll
      for (int kt = 0; kt < 2; kt++){
        bf16x8 a = *(const bf16x8*)(&sP[mt*16 + tr][kt*32 + quad*8]);
        bf16x8 b = *(const bf16x8*)(&sVt[wave*32 + nt*16 + tr][kt*32 + quad*8]);
        acc[mt][nt] = __builtin_amdgcn_mfma_f32_16x16x32_bf16(a, b, acc[mt][nt], 0, 0, 0);
      }
  __syncthreads();

#pragma unroll
  for (int mt = 0; mt < 3; mt++)
#pragma unroll
    for (int r2 = 0; r2 < 4; r2++){
      int row = mt*16 + quad*4 + r2;
      if (row < 45){
        float dinv = 1.0f / sDen[row];
        int hh = wi*5 + row/9, ww = wj*9 + row%9;
        size_t base = ((size_t)((qf*40 + hh)*72 + ww)) * 512 + head * 128;
#pragma unroll
        for (int nt = 0; nt < 2; nt++){
          int col = wave*32 + nt*16 + tr;
          yb[base + col] = f2bf(acc[mt][nt][r2] * dinv);
        }
      }
    }
}

extern "C" void kernel_launch(void* const* d_in, const int* in_sizes, int n_in,
                              void* d_out, int out_size, void* d_ws, size_t ws_size,
                              hipStream_t stream)
{
  const float* x     = (const float*)d_in[0];
  const float* masks = (const float*)d_in[1];
  const float* Wq = (const float*)d_in[2];  const float* bq = (const float*)d_in[3];
  const float* Wk = (const float*)d_in[4];  const float* bk = (const float*)d_in[5];
  const float* Wv = (const float*)d_in[6];  const float* bv = (const float*)d_in[7];
  const float* Wp = (const float*)d_in[8];  const float* bp = (const float*)d_in[9];
  const float* pw = (const float*)d_in[10]; const float* pb = (const float*)d_in[11];
  float* out = (float*)d_out;

  char* ws = (char*)d_ws;
  size_t off = 0;
  auto alloc = [&](size_t bytes) -> char* {
    char* p = ws + off; off += (bytes + 255) & ~(size_t)255; return p;
  };
  u16* wt    = (u16*)alloc((size_t)4 * 512 * 512 * 2);
  u16* xbf   = (u16*)alloc((size_t)NTOK * 512 * 2);
  u16* qbuf  = (u16*)alloc((size_t)NTOK * 512 * 2);
  u16* kbuf  = (u16*)alloc((size_t)(NTOK + 1080) * 512 * 2);   // unified: pool K rows appended
  u16* vbuf  = (u16*)alloc((size_t)(NTOK + 1080) * 512 * 2);   // unified: pool V rows appended
  u16* pxbuf = (u16*)alloc((size_t)1080 * 512 * 2);
  u16* ybuf  = (u16*)alloc((size_t)NTOK * 512 * 2);
  int* wmaskb = (int*)alloc(64 * 4);
  int* vib    = (int*)alloc(148 * 4);
  u16* pkbuf = kbuf + (size_t)NTOK * 512;
  u16* pvbuf = vbuf + (size_t)NTOK * 512;

  convert_x<<<dim3((NTOK*512/4 + 255)/256), 256, 0, stream>>>(x, xbf, NTOK*512/4);
  transpose_w<<<dim3(1024, 4), 256, 0, stream>>>(Wq, Wk, Wv, Wp, wt);
  gemm_bias<<<dim3(135, 4, 3), 256, 0, stream>>>(xbf, wt, bq, bk, bv, qbuf, kbuf, vbuf, nullptr, 0, 1, 2, QSC, NTOK);
  pool_conv<<<dim3(2160), 256, 0, stream>>>(x, pw, pb, pxbuf);
  gemm_bias<<<dim3(9, 4, 2), 256, 0, stream>>>(pxbuf, wt, bk, bv, bv, pkbuf, pvbuf, pvbuf, nullptr, 1, 2, 2, 1.f, 1080);
  prep<<<dim3(64), 64, 0, stream>>>(masks, wmaskb, vib);
  attn_dense<<<dim3(64, 4, 2), 512, 0, stream>>>(qbuf, kbuf, vbuf, wmaskb, vib, ybuf);
  attn_local<<<dim3(64, 4, 6), 256, 0, stream>>>(qbuf, kbuf, vbuf, wmaskb, ybuf);
  gemm_bias<<<dim3(135, 4, 1), 256, 0, stream>>>(ybuf, wt, bp, bp, bp, nullptr, nullptr, nullptr, out, 3, 3, 3, 1.f, NTOK);
}

// Round 8
// 479.485 us; speedup vs baseline: 1.2201x; 1.2201x over previous
//
#include <hip/hip_runtime.h>

typedef unsigned short u16;
typedef unsigned int u32;
typedef __bf16 bf16x8 __attribute__((ext_vector_type(8)));
typedef float f32x4 __attribute__((ext_vector_type(4)));

#define TT 6
#define NTOK (6*40*72)      // 17280 tokens
#define KTOT 373            // keys per frame: 45 win + 148 rolled + 180 pooled
#define NKEYS (TT*KTOT)     // 2238 dense keys
#define KC 64               // keys per chunk
#define NCH 35              // ceil(2238/64)
#define QSC 0.12751745f     // 1/sqrt(128) * log2(e), folded into Wq/bq

__device__ __forceinline__ float bf2f(u16 u){ u32 x = ((u32)u) << 16; return __builtin_bit_cast(float, x); }
__device__ __forceinline__ u16 f2bf(float f){ u32 x = __builtin_bit_cast(u32, f); x += 0x7fff + ((x >> 16) & 1); return (u16)(x >> 16); }

// ---------------- float32 -> bf16 conversion (x) ----------------
__global__ __launch_bounds__(256) void convert_x(const float* __restrict__ src, u16* __restrict__ dst, int n4)
{
  int i = blockIdx.x * 256 + threadIdx.x;
  if (i >= n4) return;
  float4 v = *(const float4*)(src + (size_t)i * 4);
  u16 o[4] = {f2bf(v.x), f2bf(v.y), f2bf(v.z), f2bf(v.w)};
  *(uint2*)(dst + (size_t)i * 4) = *(const uint2*)o;
}

// ---------------- weight transpose: out[m][n][k] = bf16(W_m[k][n]); Wq scaled by QSC ----------------
__global__ __launch_bounds__(256) void transpose_w(
    const float* __restrict__ w0, const float* __restrict__ w1,
    const float* __restrict__ w2, const float* __restrict__ w3, u16* __restrict__ out)
{
  int m = blockIdx.y;
  const float* src = m == 0 ? w0 : (m == 1 ? w1 : (m == 2 ? w2 : w3));
  float sc = (m == 0) ? QSC : 1.f;
  int idx = blockIdx.x * 256 + threadIdx.x;   // = n*512 + k
  int n = idx >> 9, k = idx & 511;
  out[m * 262144 + idx] = f2bf(src[k * 512 + n] * sc);
}

// ---------------- GEMM: C[M][512] = A[M][512] @ W + bias ----------------
__global__ __launch_bounds__(256) void gemm_bias(
    const u16* __restrict__ A, const u16* __restrict__ wt,
    const float* __restrict__ b0, const float* __restrict__ b1, const float* __restrict__ b2,
    u16* __restrict__ c0, u16* __restrict__ c1, u16* __restrict__ c2, float* __restrict__ cf,
    int wo0, int wo1, int wo2, float bsc0, int M)
{
  __shared__ __align__(16) u16 sA[128][40];
  __shared__ __align__(16) u16 sB[128][40];
  int z = blockIdx.z;
  const u16* Bt = wt + (size_t)(z == 0 ? wo0 : (z == 1 ? wo1 : wo2)) * 262144;
  const float* bias = z == 0 ? b0 : (z == 1 ? b1 : b2);
  float bsc = (z == 0) ? bsc0 : 1.f;
  u16* Cout = z == 0 ? c0 : (z == 1 ? c1 : c2);
  int mbase = blockIdx.x * 128, nbase = blockIdx.y * 128;
  int tid = threadIdx.x, lane = tid & 63, wave = tid >> 6;
  int wm = (wave >> 1) * 64, wn = (wave & 1) * 64;
  int quad = lane >> 4, tr = lane & 15;
  f32x4 acc[4][4];
#pragma unroll
  for (int i = 0; i < 4; i++)
#pragma unroll
    for (int j = 0; j < 4; j++){ acc[i][j][0]=0.f; acc[i][j][1]=0.f; acc[i][j][2]=0.f; acc[i][j][3]=0.f; }

  for (int k0 = 0; k0 < 512; k0 += 32){
    if (k0) __syncthreads();
#pragma unroll
    for (int r = 0; r < 2; r++){
      int u = tid + 256 * r;
      int row = u >> 2, kg = (u & 3) * 8;
      int grow = mbase + row;
      uint4 va = make_uint4(0,0,0,0);
      if (grow < M) va = *(const uint4*)(A + (size_t)grow * 512 + k0 + kg);
      *(uint4*)(&sA[row][kg]) = va;
      uint4 vb = *(const uint4*)(Bt + (size_t)(nbase + row) * 512 + k0 + kg);
      *(uint4*)(&sB[row][kg]) = vb;
    }
    __syncthreads();
    bf16x8 a[4], b[4];
#pragma unroll
    for (int i = 0; i < 4; i++) a[i] = *(const bf16x8*)(&sA[wm + i*16 + tr][quad * 8]);
#pragma unroll
    for (int j = 0; j < 4; j++) b[j] = *(const bf16x8*)(&sB[wn + j*16 + tr][quad * 8]);
#pragma unroll
    for (int i = 0; i < 4; i++)
#pragma unroll
      for (int j = 0; j < 4; j++)
        acc[i][j] = __builtin_amdgcn_mfma_f32_16x16x32_bf16(a[i], b[j], acc[i][j], 0, 0, 0);
  }

#pragma unroll
  for (int j = 0; j < 4; j++){
    int col = nbase + wn + j*16 + tr;
    float bv = bias[col] * bsc;
#pragma unroll
    for (int i = 0; i < 4; i++)
#pragma unroll
      for (int r2 = 0; r2 < 4; r2++){
        int row = mbase + wm + i*16 + quad*4 + r2;
        if (row < M){
          float val = acc[i][j][r2] + bv;
          if (cf) cf[(size_t)row * 512 + col] = val;
          else    Cout[(size_t)row * 512 + col] = f2bf(val);
        }
      }
  }
}

// ---------------- depthwise 4x4/4 pool conv: px[1080][512] bf16 ----------------
__global__ __launch_bounds__(256) void pool_conv(
    const float* __restrict__ x, const float* __restrict__ pw,
    const float* __restrict__ pb, u16* __restrict__ px)
{
  int idx = blockIdx.x * 256 + threadIdx.x;
  int c = idx & 511, n = idx >> 9;
  int f = n / 180, rp = n % 180, ph = rp / 18, pwc = rp % 18;
  float acc = pb[c];
#pragma unroll
  for (int i = 0; i < 4; i++)
#pragma unroll
    for (int j = 0; j < 4; j++){
      int hh = ph*4 + i, ww = pwc*4 + j;
      acc += x[((size_t)((f*40 + hh)*72 + ww)) * 512 + c] * pw[(i*4 + j)*512 + c];
    }
  px[idx] = f2bf(acc);
}

// ---------------- window mask + VALID_IND compaction (parallel) ----------------
__global__ __launch_bounds__(64) void prep(const float* __restrict__ masks, int* __restrict__ wmask, int* __restrict__ vi)
{
  int win = blockIdx.x, tid = threadIdx.x;
  int wi = win >> 3, wj = win & 7;
  int flag = 0;
  for (int p = tid; p < 270; p += 64){   // p = f*45 + pos
    int f = p / 45, pos = p - f*45;
    int hh = wi*5 + pos/9, ww = wj*9 + pos%9;
    if (masks[(f*40 + hh)*72 + ww] > 0.f) flag = 1;
  }
  unsigned long long b = __ballot(flag);
  if (tid == 0) wmask[win] = (b != 0ULL) ? 1 : 0;
  if (win == 0 && tid == 0){
    int cnt = 0;
    for (int e = 0; e < 180; e++){
      int s = e / 45, pos = e % 45, pr = pos / 9, pc = pos % 9;
      bool inval = (s == 0 && pr < 2 && pc < 4) || (s == 1 && pr < 2 && pc >= 5) ||
                   (s == 2 && pr >= 3 && pc < 4) || (s == 3 && pr >= 3 && pc >= 5);
      if (!inval) vi[cnt++] = e;
    }
  }
}

// ================= DENSE attention =================
// Block = (window, head, third). third covers 2 frames = 90 q-rows (96 padded)
// = EXACTLY 6 m-tiles; 384 threads = 6 waves, wave w owns tile w. No shared
// tile, no cross-wave choreography [fixes round 4-7 tile-8 saga].
// KC=64 keys/chunk, 35 chunks. LDS 53.5 KB, __launch_bounds__(384,3) ->
// 2 blocks/CU resident with a 170-reg budget: live set ~90 regs, NO SPILL
// [round-6/7 lesson: (512,4)'s 128-reg cap forced 190 MB of scratch traffic].
__global__ __launch_bounds__(384, 3) void attn_dense(
    const u16* __restrict__ qb, const u16* __restrict__ kb, const u16* __restrict__ vb,
    const int* __restrict__ wmaskp, const int* __restrict__ vip,
    u16* __restrict__ yb)
{
  __shared__ __align__(16) u16 sK[64][136];   // key chunk [key][hd]
  __shared__ __align__(16) u16 sVt[128][72];  // V^T [hd][key]
  __shared__ __align__(16) u16 sP[96][72];    // exp(S) bf16 [row][key]
  __shared__ u16 sIdx16[2240];                // key -> unified row (pool rows at NTOK+)
  __shared__ int sVI[148];

  int win = blockIdx.x, head = blockIdx.y, third = blockIdx.z;
  if (!wmaskp[win]) return;
  int wi = win >> 3, wj = win & 7;
  int tid = threadIdx.x, lane = tid & 63, wave = tid >> 6;
  int quad = lane >> 4, tr = lane & 15;
  int hoff = head * 128;

  if (tid < 148) sVI[tid] = vip[tid];
  __syncthreads();

  // ---- per-window gather table (u16 unified row indices) ----
  for (int i = tid; i < 2240; i += 384){
    int v = 0;
    if (i < NKEYS){
      int f = i / KTOT, slot = i - f * KTOT;
      if (slot < 45){
        v = (f*40 + wi*5 + slot/9)*72 + wj*9 + slot%9;
      } else if (slot < 193){
        int e = sVI[slot - 45];
        int s2 = e/45, pos = e - s2*45, pr = pos/9, pc = pos - pr*9;
        int hh = wi*5 + pr + ((s2 < 2) ? 3 : -3);
        int ww = wj*9 + pc + ((s2 & 1) ? -5 : 5);
        if (hh < 0) hh += 40; else if (hh >= 40) hh -= 40;
        if (ww < 0) ww += 72; else if (ww >= 72) ww -= 72;
        v = (f*40 + hh)*72 + ww;
      } else {
        v = NTOK + f*180 + (slot - 193);
      }
    }
    sIdx16[i] = (u16)v;
  }

  // ---- Q fragments in registers (own tile; rows third*90 + wave*16 + tr) ----
  bf16x8 qf[4];
  {
    int rl = wave*16 + tr;               // 0..95 local row
    bool vq = rl < 90;
    int rc = vq ? rl : 0;
    int f = 2*third + rc/45, r = rc % 45;
    const u16* qp = qb + ((size_t)((f*40 + wi*5 + r/9)*72 + wj*9 + r%9))*512 + hoff;
#pragma unroll
    for (int kt = 0; kt < 4; kt++){
      uint4 v = make_uint4(0,0,0,0);
      if (vq) v = *(const uint4*)(qp + kt*32 + quad*8);
      qf[kt] = __builtin_bit_cast(bf16x8, v);
    }
  }

  f32x4 accv[8];
#pragma unroll
  for (int nt = 0; nt < 8; nt++){ accv[nt][0]=0.f; accv[nt][1]=0.f; accv[nt][2]=0.f; accv[nt][3]=0.f; }
  float dacc[4] = {0.f,0.f,0.f,0.f};

  __syncthreads();   // sIdx16 ready

  // register prefetch: 1024 uint4 (K) + 1024 (V) per chunk over 384 threads -> 3 rounds, last partial
  uint4 pfk[3], pfv[3];
  auto pref = [&](int ch){
#pragma unroll
    for (int r = 0; r < 3; r++){ pfk[r] = make_uint4(0,0,0,0); pfv[r] = make_uint4(0,0,0,0); }
    if (ch < NCH){
#pragma unroll
      for (int r = 0; r < 3; r++){
        int u = tid + 384*r;
        if (u < 1024){
          int jgk = ch*64 + (u >> 4);
          if (jgk < NKEYS)
            pfk[r] = *(const uint4*)(kb + ((size_t)sIdx16[jgk] << 9) + hoff + (u & 15)*8);
          int jgv = ch*64 + (u & 63);
          if (jgv < NKEYS)
            pfv[r] = *(const uint4*)(vb + ((size_t)sIdx16[jgv] << 9) + hoff + (u >> 6)*8);
        }
      }
    }
  };
  pref(0);

  for (int ch = 0; ch < NCH; ch++){
    __syncthreads();               // prev PV done; sK/sVt free
#pragma unroll
    for (int r = 0; r < 3; r++){
      int u = tid + 384*r;
      if (u < 1024){
        *(uint4*)(&sK[u >> 4][(u & 15)*8]) = pfk[r];
        int keyv = u & 63, dgv = u >> 6;
        u32 vv[4] = {pfv[r].x, pfv[r].y, pfv[r].z, pfv[r].w};
#pragma unroll
        for (int q2 = 0; q2 < 4; q2++){
          sVt[dgv*8 + q2*2][keyv]     = (u16)(vv[q2] & 0xffff);
          sVt[dgv*8 + q2*2 + 1][keyv] = (u16)(vv[q2] >> 16);
        }
      }
    }
    __syncthreads();               // staged
    pref(ch + 1);                  // overlap next gather with compute

    // ---- QK^T + exp2 (Q pre-scaled by 1/sqrt(hd)*log2e) ----
#pragma unroll
    for (int nt = 0; nt < 4; nt++){
      bf16x8 bk4[4];
#pragma unroll
      for (int kt = 0; kt < 4; kt++) bk4[kt] = *(const bf16x8*)(&sK[nt*16 + tr][kt*32 + quad*8]);
      int colg = ch*64 + nt*16 + tr;
      bool vld = colg < NKEYS;
      f32x4 s = {0.f, 0.f, 0.f, 0.f};
#pragma unroll
      for (int kt = 0; kt < 4; kt++) s = __builtin_amdgcn_mfma_f32_16x16x32_bf16(qf[kt], bk4[kt], s, 0, 0, 0);
#pragma unroll
      for (int r2 = 0; r2 < 4; r2++){
        float p = vld ? __builtin_amdgcn_exp2f(s[r2]) : 0.f;   // no max-sub: logits small
        u16 pb2 = f2bf(p);
        sP[wave*16 + quad*4 + r2][nt*16 + tr] = pb2;
        dacc[r2] += bf2f(pb2);
      }
    }
    __syncthreads();               // sP complete

    // ---- PV: own tile, all 8 hd-tiles ----
#pragma unroll
    for (int kt = 0; kt < 2; kt++){
      bf16x8 a = *(const bf16x8*)(&sP[wave*16 + tr][kt*32 + quad*8]);
#pragma unroll
      for (int nt = 0; nt < 8; nt++){
        bf16x8 bv = *(const bf16x8*)(&sVt[nt*16 + tr][kt*32 + quad*8]);
        accv[nt] = __builtin_amdgcn_mfma_f32_16x16x32_bf16(a, bv, accv[nt], 0, 0, 0);
      }
    }
  }

  // ---- epilogue: den reduction in registers, divide, scatter ----
#pragma unroll
  for (int r2 = 0; r2 < 4; r2++){
    float d = dacc[r2];
    d += __shfl_xor(d, 1, 64); d += __shfl_xor(d, 2, 64);
    d += __shfl_xor(d, 4, 64); d += __shfl_xor(d, 8, 64);
    float dinv = 1.f / d;
    int rl = wave*16 + quad*4 + r2;
    if (rl < 90){
      int f = 2*third + rl/45, r = rl % 45;
      size_t base = ((size_t)((f*40 + wi*5 + r/9)*72 + wj*9 + r%9))*512 + hoff;
#pragma unroll
      for (int nt = 0; nt < 8; nt++)
        yb[base + nt*16 + tr] = f2bf(accv[nt][r2] * dinv);
    }
  }
}

// ---------------- LOCAL (unmasked) windows: per-frame 45-key attention ----------------
__device__ __forceinline__ const u16* key_src_local(int slot, int qf, int wi, int wj, int head,
    const u16* __restrict__ tokbuf)
{
  int hh = wi*5 + slot/9, ww = wj*9 + slot%9;
  return tokbuf + ((size_t)((qf*40 + hh)*72 + ww)) * 512 + head * 128;
}

__global__ __launch_bounds__(256) void attn_local(
    const u16* __restrict__ qb, const u16* __restrict__ kb, const u16* __restrict__ vb,
    const int* __restrict__ wmaskp, u16* __restrict__ yb)
{
  __shared__ __align__(16) u16 sQ[48][136];
  __shared__ __align__(16) u16 sK[64][136];
  __shared__ __align__(16) u16 sVt[128][72];
  __shared__ __align__(16) u16 sP[48][72];
  __shared__ float sDen[48];

  int win = blockIdx.x, head = blockIdx.y, qf = blockIdx.z;
  if (wmaskp[win]) return;
  int wi = win >> 3, wj = win & 7;
  int tid = threadIdx.x, lane = tid & 63, wave = tid >> 6;
  int quad = lane >> 4, tr = lane & 15;

  if (tid < 48) sDen[tid] = 0.f;

#pragma unroll
  for (int r = 0; r < 3; r++){
    int u = tid + 256 * r;
    int row = u >> 4, dg = u & 15;
    uint4 val = make_uint4(0,0,0,0);
    if (row < 45){
      int hh = wi*5 + row/9, ww = wj*9 + row%9;
      val = *(const uint4*)(qb + ((size_t)((qf*40 + hh)*72 + ww)) * 512 + head*128 + dg*8);
    }
    *(uint4*)(&sQ[row][dg * 8]) = val;
  }

  const int nkeys = 45;
  f32x4 acc[3][2];
#pragma unroll
  for (int a = 0; a < 3; a++)
#pragma unroll
    for (int b = 0; b < 2; b++){ acc[a][b][0]=0.f; acc[a][b][1]=0.f; acc[a][b][2]=0.f; acc[a][b][3]=0.f; }

#pragma unroll
  for (int r = 0; r < 4; r++){
    int u = tid + 256 * r;
    int key = u >> 4, dg = u & 15;
    uint4 val = make_uint4(0,0,0,0);
    if (key < nkeys) val = *(const uint4*)(key_src_local(key, qf, wi, wj, head, kb) + dg * 8);
    *(uint4*)(&sK[key][dg * 8]) = val;
  }
#pragma unroll
  for (int r = 0; r < 4; r++){
    int u = tid + 256 * r;
    int key = u & 63, dg = u >> 6;
    uint4 val = make_uint4(0,0,0,0);
    if (key < nkeys) val = *(const uint4*)(key_src_local(key, qf, wi, wj, head, vb) + dg * 8);
    u32 vv[4] = {val.x, val.y, val.z, val.w};
#pragma unroll
    for (int q2 = 0; q2 < 4; q2++){
      sVt[dg*8 + q2*2][key]     = (u16)(vv[q2] & 0xffff);
      sVt[dg*8 + q2*2 + 1][key] = (u16)(vv[q2] >> 16);
    }
  }
  __syncthreads();

#pragma unroll
  for (int mt = 0; mt < 3; mt++){
    f32x4 sacc = {0.f, 0.f, 0.f, 0.f};
#pragma unroll
    for (int kt = 0; kt < 4; kt++){
      bf16x8 a = *(const bf16x8*)(&sQ[mt*16 + tr][kt*32 + quad*8]);
      bf16x8 b = *(const bf16x8*)(&sK[wave*16 + tr][kt*32 + quad*8]);
      sacc = __builtin_amdgcn_mfma_f32_16x16x32_bf16(a, b, sacc, 0, 0, 0);
    }
    int colg = wave * 16 + tr;
    float pr4[4];
#pragma unroll
    for (int r2 = 0; r2 < 4; r2++){
      float p = (colg < nkeys) ? __builtin_amdgcn_exp2f(sacc[r2]) : 0.f;  // Q pre-scaled
      u16 pb2 = f2bf(p);
      sP[mt*16 + quad*4 + r2][wave*16 + tr] = pb2;
      pr4[r2] = bf2f(pb2);
    }
#pragma unroll
    for (int r2 = 0; r2 < 4; r2++){
      float ps = pr4[r2];
      ps += __shfl_xor(ps, 1, 64);
      ps += __shfl_xor(ps, 2, 64);
      ps += __shfl_xor(ps, 4, 64);
      ps += __shfl_xor(ps, 8, 64);
      if (tr == 0) atomicAdd(&sDen[mt*16 + quad*4 + r2], ps);
    }
  }
  __syncthreads();

#pragma unroll
  for (int mt = 0; mt < 3; mt++)
#pragma unroll
    for (int nt = 0; nt < 2; nt++)
#pragma unroll
      for (int kt = 0; kt < 2; kt++){
        bf16x8 a = *(const bf16x8*)(&sP[mt*16 + tr][kt*32 + quad*8]);
        bf16x8 b = *(const bf16x8*)(&sVt[wave*32 + nt*16 + tr][kt*32 + quad*8]);
        acc[mt][nt] = __builtin_amdgcn_mfma_f32_16x16x32_bf16(a, b, acc[mt][nt], 0, 0, 0);
      }
  __syncthreads();

#pragma unroll
  for (int mt = 0; mt < 3; mt++)
#pragma unroll
    for (int r2 = 0; r2 < 4; r2++){
      int row = mt*16 + quad*4 + r2;
      if (row < 45){
        float dinv = 1.0f / sDen[row];
        int hh = wi*5 + row/9, ww = wj*9 + row%9;
        size_t base = ((size_t)((qf*40 + hh)*72 + ww)) * 512 + head * 128;
#pragma unroll
        for (int nt = 0; nt < 2; nt++){
          int col = wave*32 + nt*16 + tr;
          yb[base + col] = f2bf(acc[mt][nt][r2] * dinv);
        }
      }
    }
}

extern "C" void kernel_launch(void* const* d_in, const int* in_sizes, int n_in,
                              void* d_out, int out_size, void* d_ws, size_t ws_size,
                              hipStream_t stream)
{
  const float* x     = (const float*)d_in[0];
  const float* masks = (const float*)d_in[1];
  const float* Wq = (const float*)d_in[2];  const float* bq = (const float*)d_in[3];
  const float* Wk = (const float*)d_in[4];  const float* bk = (const float*)d_in[5];
  const float* Wv = (const float*)d_in[6];  const float* bv = (const float*)d_in[7];
  const float* Wp = (const float*)d_in[8];  const float* bp = (const float*)d_in[9];
  const float* pw = (const float*)d_in[10]; const float* pb = (const float*)d_in[11];
  float* out = (float*)d_out;

  char* ws = (char*)d_ws;
  size_t off = 0;
  auto alloc = [&](size_t bytes) -> char* {
    char* p = ws + off; off += (bytes + 255) & ~(size_t)255; return p;
  };
  u16* wt    = (u16*)alloc((size_t)4 * 512 * 512 * 2);
  u16* xbf   = (u16*)alloc((size_t)NTOK * 512 * 2);
  u16* qbuf  = (u16*)alloc((size_t)NTOK * 512 * 2);
  u16* kbuf  = (u16*)alloc((size_t)(NTOK + 1080) * 512 * 2);   // unified: pool K rows appended
  u16* vbuf  = (u16*)alloc((size_t)(NTOK + 1080) * 512 * 2);   // unified: pool V rows appended
  u16* pxbuf = (u16*)alloc((size_t)1080 * 512 * 2);
  u16* ybuf  = (u16*)alloc((size_t)NTOK * 512 * 2);
  int* wmaskb = (int*)alloc(64 * 4);
  int* vib    = (int*)alloc(148 * 4);
  u16* pkbuf = kbuf + (size_t)NTOK * 512;
  u16* pvbuf = vbuf + (size_t)NTOK * 512;

  convert_x<<<dim3((NTOK*512/4 + 255)/256), 256, 0, stream>>>(x, xbf, NTOK*512/4);
  transpose_w<<<dim3(1024, 4), 256, 0, stream>>>(Wq, Wk, Wv, Wp, wt);
  gemm_bias<<<dim3(135, 4, 3), 256, 0, stream>>>(xbf, wt, bq, bk, bv, qbuf, kbuf, vbuf, nullptr, 0, 1, 2, QSC, NTOK);
  pool_conv<<<dim3(2160), 256, 0, stream>>>(x, pw, pb, pxbuf);
  gemm_bias<<<dim3(9, 4, 2), 256, 0, stream>>>(pxbuf, wt, bk, bv, bv, pkbuf, pvbuf, pvbuf, nullptr, 1, 2, 2, 1.f, 1080);
  prep<<<dim3(64), 64, 0, stream>>>(masks, wmaskb, vib);
  attn_dense<<<dim3(64, 4, 3), 384, 0, stream>>>(qbuf, kbuf, vbuf, wmaskb, vib, ybuf);
  attn_local<<<dim3(64, 4, 6), 256, 0, stream>>>(qbuf, kbuf, vbuf, wmaskb, ybuf);
  gemm_bias<<<dim3(135, 4, 1), 256, 0, stream>>>(ybuf, wt, bp, bp, bp, nullptr, nullptr, nullptr, out, 3, 3, 3, 1.f, NTOK);
}